// Round 8
// baseline (274.239 us; speedup 1.0000x reference)
//
#include <hip/hip_runtime.h>
#include <math.h>

// SLIC superpixel segmentation — bit-faithful f32 reimplementation of the JAX ref
// (XLA CPU semantics). Numerics decisions, all aimed at exact label match:
//  - dot(feats, centers) replicates Eigen sgemm: sequential k=0..4 FMA chain.
//  - f_sq / c_sq: rounded squares, sequential adds, NO fma (fp contract off).
//  - d = (f_sq + c_sq) - 2*dot, three separately-rounded ops.
//  - argmin == first-min: (d < dmin) || (d == dmin && k < kbest) — order-free.
//  - segment_sum: EXACT ascending-pixel-index sequential adds per cluster.
// R25-R27 (264->257.8us): instruction-level cuts inside assign/update were
// near-neutral -> dispatches are dominated by per-dispatch ramp + per-BLOCK
// fixed overhead (centers chain, whist zero/prefix, scans, descriptors), not
// the per-pixel stream.
// R28: amortize fixed costs 2x — TPX 512->1024 (4 px/thread, 392 blocks,
// NTILE=49). Per-block fixed work paid half as often; 392 blocks = 1.5/CU
// guaranteed single-round residency (784 was 3.06/CU marginal). Counting sort
// keeps exact ascending-n order via 16 groups (g=p*4+w, p in 0..3). Update
// scan: 49 descriptors -> one wave-scan, no carry loop. R19's TPX=1024 loss
// was the 31KB-LDS structure; assign LDS is now 10.4KB — no occupancy cliff.
// Same integers, same float op order -> bit-identical outputs.

#pragma clang fp contract(off)

#define BATCH 8
#define HH 224
#define WW 224
#define HWPIX (HH * WW)        // 50176
#define KSEG 100
#define TPX 1024               // pixels per tile
#define NTILE 49               // 1024-px tiles per batch (49*1024 == 50176)
#define PPT 4                  // pixels per thread
#define NGRP 16                // sort groups: g = p*4 + w
#define NITER 10
#define UCH 1024               // update output chunk
#define UPITCH (UCH + 4)       // row stride: 4112B = 257*16, 16B-aligned

__device__ __forceinline__ float get_ratio() {
    double S = sqrt((double)(HH * WW) / (double)KSEG);
    return (float)(10.0 / S);
}

// 4 pixels/thread: n = tile*1024 + p*256 + tid. Ascending n == lex (p, w, lane).
// mode 2: first iteration — init centers computed locally (== old k_init),
//         tile-0 also writes them to global; then argmin + sort as mode 0.
// mode 0: argmin (pruned) + tile-local counting sort -> tileIdx + cntStart.
// mode 1: final outputs only.
__global__ void k_assign(const float* __restrict__ img, float* __restrict__ centers,
                         int* __restrict__ tileIdx, int2* __restrict__ cntStart,
                         float* __restrict__ outLab, float* __restrict__ outMean,
                         int mode) {
#pragma clang fp contract(off)
    __shared__ float c8[KSEG * 8];      // [c0..c4, csq, pad, pad]
    __shared__ int whist[NGRP * KSEG];  // group g = p*4 + w; becomes excl. prefix
    __shared__ int tilecnt[KSEG];
    __shared__ int loffs[KSEG];
    int b = blockIdx.y, tile = blockIdx.x, tid = threadIdx.x;
    int lane = tid & 63, w = tid >> 6;
    float ratio = get_ratio();

    // ---- phase 0: centers k-major into registers, csq seq-adds, ONE LDS write
    if (mode == 2) {
        // init centers locally: pure function of img, identical exprs to the
        // old k_init -> bit-identical values.
        if (tid < KSEG) {
            int k = tid;
            int i = k / 10, j = k % 10;
            int y = (int)floor(((i + 0.5) * (double)HH) / 10.0);
            int x = (int)floor(((j + 0.5) * (double)WW) / 10.0);
            int n = y * WW + x;
            const float* p = img + ((size_t)b * HWPIX + n) * 3;
            float c0 = (float)y * ratio, c1 = (float)x * ratio;
            float c2 = p[0], c3 = p[1], c4 = p[2];
            float s = c0 * c0;               // XLA fused mul+reduce: no fma
            s = s + c1 * c1;
            s = s + c2 * c2;
            s = s + c3 * c3;
            s = s + c4 * c4;
            float* cw = c8 + k * 8;
            cw[0] = c0; cw[1] = c1; cw[2] = c2; cw[3] = c3; cw[4] = c4; cw[5] = s;
            if (tile == 0) {     // global init: covers total==0 keep-old case
                float* c = centers + (b * KSEG + k) * 5;
                c[0] = c0; c[1] = c1; c[2] = c2; c[3] = c3; c[4] = c4;
            }
        }
    } else {
        if (tid < KSEG) {
            const float* cg = centers + ((size_t)b * KSEG + tid) * 5;
            float c0 = cg[0], c1 = cg[1], c2 = cg[2], c3 = cg[3], c4 = cg[4];
            float s = c0 * c0;               // same seq-add order as ever
            s = s + c1 * c1;
            s = s + c2 * c2;
            s = s + c3 * c3;
            s = s + c4 * c4;
            float* cw = c8 + tid * 8;
            cw[0] = c0; cw[1] = c1; cw[2] = c2; cw[3] = c3; cw[4] = c4; cw[5] = s;
        }
    }
    if (mode != 1)
        for (int i = tid; i < NGRP * KSEG; i += 256) whist[i] = 0;

    // ---- pixel features (registers only; overlaps the loads above)
    int n0 = tile * TPX + tid;
    float yf[PPT], xf[PPT], rr[PPT], gg[PPT], bb[PPT], fsq[PPT], dmin[PPT];
    int kb[PPT];
#pragma unroll
    for (int p = 0; p < PPT; ++p) {
        int n = n0 + p * 256;
        int y = n / WW, x = n - y * WW;
        yf[p] = (float)y * ratio;
        xf[p] = (float)x * ratio;
        const float* pp = img + ((size_t)b * HWPIX + n) * 3;
        rr[p] = pp[0]; gg[p] = pp[1]; bb[p] = pp[2];
        float s = yf[p] * yf[p];             // no fma, seq adds (XLA reduce)
        s = s + xf[p] * xf[p];
        s = s + rr[p] * rr[p];
        s = s + gg[p] * gg[p];
        s = s + bb[p] * bb[p];
        fsq[p] = s;
        dmin[p] = INFINITY;
        kb[p] = 0;
    }
    __syncthreads();                                 // (A) c8 + whist ready

    // evaluate one cluster exactly (reference op order); order-free first-min rule
#define EVALK(kk)                                                              \
    {                                                                          \
        int k_ = (kk);                                                         \
        float4 v0 = *reinterpret_cast<const float4*>(&c8[k_ * 8]);             \
        float2 v1 = *reinterpret_cast<const float2*>(&c8[k_ * 8 + 4]);         \
        _Pragma("unroll")                                                      \
        for (int p = 0; p < PPT; ++p) {                                        \
            float dot = yf[p] * v0.x;                                          \
            dot = __fmaf_rn(xf[p], v0.y, dot);                                 \
            dot = __fmaf_rn(rr[p], v0.z, dot);                                 \
            dot = __fmaf_rn(gg[p], v0.w, dot);                                 \
            dot = __fmaf_rn(bb[p], v1.x, dot);                                 \
            float d = (fsq[p] + v1.y) - 2.0f * dot;                            \
            if (d < dmin[p] || (d == dmin[p] && k_ < kb[p])) {                 \
                dmin[p] = d; kb[p] = k_;                                       \
            }                                                                  \
        }                                                                      \
    }

    // ---- phase A: statically nearest cluster grid rows (ascending k)
    int y0t = (tile * TPX) / WW, y1t = (tile * TPX + TPX - 1) / WW;
    int rmid = ((y0t + y1t) / 2) * 10 / HH;          // nearest init grid row
    int rlo = (rmid > 0) ? rmid - 1 : 0;
    int rhi = (rmid < 9) ? rmid + 1 : 9;
    int kA0 = rlo * 10, kA1 = rhi * 10 + 10;         // 20..30 clusters
    for (int k = kA0; k < kA1; ++k) EVALK(k);

    // ---- per-WAVE max dmin + rigorous margin (no LDS, no barriers)
    float tmax = fmaxf(fmaxf(dmin[0], dmin[1]), fmaxf(dmin[2], dmin[3]));
    for (int d = 32; d > 0; d >>= 1) tmax = fmaxf(tmax, __shfl_xor(tmax, d));
    float dmaxW = tmax + 1.0f;

    // ---- per-wave keep-mask: remaining ks whose y lower bound could still win
    unsigned long long m0, m1;
    {
        int k1 = lane;                               // k 0..63
        bool instat1 = (k1 >= kA0 && k1 < kA1);
        float cyf1 = c8[k1 * 8 + 0];
        float t01 = (float)y0t * ratio - cyf1;       // cy below tile range
        float t11 = cyf1 - (float)y1t * ratio;       // cy above tile range
        float t1v = fmaxf(fmaxf(t01, t11), 0.0f);
        m0 = __ballot((!instat1) && (t1v * t1v <= dmaxW));
        int k2 = 64 + lane;                          // k 64..99 (lane<36)
        bool keep2 = false;
        if (k2 < KSEG) {
            bool instat2 = (k2 >= kA0 && k2 < kA1);
            float cyf2 = c8[k2 * 8 + 0];
            float t02 = (float)y0t * ratio - cyf2;
            float t12 = cyf2 - (float)y1t * ratio;
            float t2v = fmaxf(fmaxf(t02, t12), 0.0f);
            keep2 = (!instat2) && (t2v * t2v <= dmaxW);
        }
        m1 = __ballot(keep2);
    }

    // ---- phase B: surviving clusters (ascending k within each word)
    while (m0) { int k = __builtin_ctzll(m0); m0 &= m0 - 1; EVALK(k); }
    while (m1) { int k = 64 + __builtin_ctzll(m1); m1 &= m1 - 1; EVALK(k); }
#undef EVALK

    if (mode == 1) {
#pragma unroll
        for (int p = 0; p < PPT; ++p) {
            int n = n0 + p * 256;
            outLab[(size_t)b * HWPIX + n] = (float)kb[p];
            float* om = outMean + ((size_t)b * HWPIX + n) * 3;
            om[0] = c8[kb[p] * 8 + 2];
            om[1] = c8[kb[p] * 8 + 3];
            om[2] = c8[kb[p] * 8 + 4];
        }
        return;
    }

    // ---- tile-local stable counting sort (order: p, wave, lane == ascending n)
    // Leader-ballot rank over DISTINCT labels present in the wave.
    unsigned long long lmask_lt = (lane == 0) ? 0ull : (~0ull >> (64 - lane));
    int rank_w[PPT], cnt_w[PPT];
#pragma unroll
    for (int p = 0; p < PPT; ++p) {
        unsigned long long todo = __ballot(1);       // all active lanes
        while (todo) {
            int leader = __builtin_ctzll(todo);
            int lval = __shfl(kb[p], leader);
            unsigned long long mset = __ballot(kb[p] == lval);
            if (kb[p] == lval) {
                cnt_w[p] = (int)__popcll(mset);
                rank_w[p] = (int)__popcll(mset & lmask_lt);
            }
            todo &= ~mset;
        }
    }
#pragma unroll
    for (int p = 0; p < PPT; ++p)
        if (rank_w[p] == 0) whist[(p * 4 + w) * KSEG + kb[p]] = cnt_w[p];
    __syncthreads();                                 // (B)
    if (tid < KSEG) {
        int s = 0;
#pragma unroll
        for (int g = 0; g < NGRP; ++g) {             // sum AND leave exclusive
            int t = whist[g * KSEG + tid];           // prefix in place
            whist[g * KSEG + tid] = s;
            s += t;
        }
        tilecnt[tid] = s;
    }
    __syncthreads();                                 // (C)
    // exclusive scan of tilecnt[100]: ONE wave, two chunks, in-wave carry
    if (tid < 64) {
        int v = tilecnt[lane];
        int incl = v;
        for (int d = 1; d < 64; d <<= 1) {
            int t = __shfl_up(incl, d);
            if (lane >= d) incl += t;
        }
        loffs[lane] = incl - v;
        int carry = __shfl(incl, 63);
        int i2 = 64 + lane;                          // k 64..99
        int v2 = (i2 < KSEG) ? tilecnt[i2] : 0;
        int incl2 = v2;
        for (int d = 1; d < 64; d <<= 1) {
            int t = __shfl_up(incl2, d);
            if (lane >= d) incl2 += t;
        }
        if (i2 < KSEG) loffs[i2] = carry + incl2 - v2;
    }
    __syncthreads();                                 // (D)
    if (tid < KSEG) {
        cntStart[((size_t)b * KSEG + tid) * NTILE + tile] =
            make_int2(tilecnt[tid], loffs[tid]);     // one dwordx2
    }

    // ---- DIRECT global scatter of sorted pixel indices (same integers as an
    // LDS-stage+copy; same-label lanes hit consecutive addresses)
    int* tb = tileIdx + (size_t)(b * NTILE + tile) * TPX;
#pragma unroll
    for (int p = 0; p < PPT; ++p) {
        int g = p * 4 + w;
        int pos = loffs[kb[p]] + rank_w[p] + whist[g * KSEG + kb[p]];
        tb[pos] = n0 + p * 256;                      // pixel index, asc per seg
    }
}

// One block per (batch,cluster). Single wave-scan of the 49 descriptors ->
// dstL (+total sentinel). Per chunk: parallel per-TILE fill of nmap (thread t
// streams its tile's intersection of the chunk from tileIdx — independent,
// pipelined loads), then all 256 threads gather: RE-DERIVE the 5 channels
// (y=n/224 exact int div; yf=(float)y*ratio identical expression to assign;
// r,g,b from img) into ubuf. Then 5 lanes run the EXACT ascending serial
// chains via pipelined float4 LDS reads (x,y,z,w index order).
__global__ void k_update(const float* __restrict__ img, const int* __restrict__ tileIdx,
                         const int2* __restrict__ cntStart, float* __restrict__ centers) {
#pragma clang fp contract(off)
    __shared__ int srcL[NTILE];
    __shared__ int dstL[NTILE + 1];
    __shared__ int nmap[UCH];
    __shared__ float ubuf[5][UPITCH];
    int k = blockIdx.x, b = blockIdx.y, tid = threadIdx.x;
    int lane = tid & 63;
    float ratio = get_ratio();

    if (tid < 64) {                          // NTILE=49 <= 64: one scan pass
        int2 cs = (lane < NTILE)
            ? cntStart[((size_t)b * KSEG + k) * NTILE + lane] : make_int2(0, 0);
        int incl = cs.x;
        for (int d = 1; d < 64; d <<= 1) {   // Hillis-Steele inclusive scan
            int t = __shfl_up(incl, d);
            if (lane >= d) incl += t;
        }
        if (lane < NTILE) { srcL[lane] = cs.y; dstL[lane] = incl - cs.x; }
        if (lane == 63) dstL[NTILE] = incl;  // lanes 49..63 add 0 -> total
    }
    __syncthreads();
    int total = dstL[NTILE];

    float acc = 0.f;
    for (int c0 = 0; c0 < total; c0 += UCH) {
        int m = min(UCH, total - c0);
        // ---- parallel fill: thread t streams its tile's slice of this chunk
        if (tid < NTILE) {
            int t = tid;
            int d0 = dstL[t], d1 = dstL[t + 1];
            int lo = d0 > c0 ? d0 : c0;
            int hi = d1 < c0 + m ? d1 : c0 + m;
            if (lo < hi) {
                const int* tip = tileIdx + (size_t)(b * NTILE + t) * TPX
                                 + (srcL[t] + (lo - d0));
                for (int i = lo; i < hi; ++i)
                    nmap[i - c0] = tip[i - lo];      // independent loads, pipeline
            }
        }
        __syncthreads();
        // ---- gather: short chain nmap(LDS) -> img
        for (int jj = tid; jj < m; jj += 256) {
            int n = nmap[jj];
            int y = n / WW, x = n - y * WW;  // exact integer magic-div
            const float* pp = img + ((size_t)b * HWPIX + n) * 3;
            ubuf[0][jj] = (float)y * ratio;  // bit-identical to assign's yf
            ubuf[1][jj] = (float)x * ratio;
            ubuf[2][jj] = pp[0];
            ubuf[3][jj] = pp[1];
            ubuf[4][jj] = pp[2];
        }
        __syncthreads();
        if (tid < 5) {
            float a = acc;
            const float4* bp4 = reinterpret_cast<const float4*>(&ubuf[tid][0]);
            int nf4 = m >> 2;
#pragma unroll 4
            for (int i = 0; i < nf4; ++i) {  // loads pipeline; adds ascending
                float4 v = bp4[i];
                a = a + v.x;
                a = a + v.y;
                a = a + v.z;
                a = a + v.w;
            }
            for (int i = nf4 << 2; i < m; ++i) a = a + ubuf[tid][i];
            acc = a;
        }
        __syncthreads();
    }
    if (tid < 5 && total > 0) {              // where(counts>0, sums/counts, old)
        centers[(b * KSEG + k) * 5 + tid] = acc / (float)total;
    }
}

extern "C" void kernel_launch(void* const* d_in, const int* in_sizes, int n_in,
                              void* d_out, int out_size, void* d_ws, size_t ws_size,
                              hipStream_t stream) {
    const float* img = (const float*)d_in[0];
    float* outLab = (float*)d_out;                         // [8,224,224] labels as f32
    float* outMean = outLab + (size_t)BATCH * HWPIX;       // [8,224,224,3]

    char* ws = (char*)d_ws;
    float* centers = (float*)ws;  ws += (size_t)BATCH * KSEG * 5 * sizeof(float);
    int* tileIdx   = (int*)ws;    ws += (size_t)BATCH * NTILE * TPX * sizeof(int);
    int2* cntStart = (int2*)ws;   ws += (size_t)BATCH * KSEG * NTILE * sizeof(int2);

    for (int it = 0; it < NITER; ++it) {
        k_assign<<<dim3(NTILE, BATCH), 256, 0, stream>>>(
            img, centers, tileIdx, cntStart, outLab, outMean, it == 0 ? 2 : 0);
        k_update<<<dim3(KSEG, BATCH), 256, 0, stream>>>(img, tileIdx, cntStart,
                                                        centers);
    }
    k_assign<<<dim3(NTILE, BATCH), 256, 0, stream>>>(
        img, centers, tileIdx, cntStart, outLab, outMean, 1);
}

// Round 9
// 258.198 us; speedup vs baseline: 1.0621x; 1.0621x over previous
//
#include <hip/hip_runtime.h>
#include <math.h>

// SLIC superpixel segmentation — bit-faithful f32 reimplementation of the JAX ref
// (XLA CPU semantics). Numerics decisions, all aimed at exact label match:
//  - dot(feats, centers) replicates Eigen sgemm: sequential k=0..4 FMA chain.
//  - f_sq / c_sq: rounded squares, sequential adds, NO fma (fp contract off).
//  - d = (f_sq + c_sq) - 2*dot, three separately-rounded ops.
//  - argmin == first-min: (d < dmin) || (d == dmin && k < kbest) — order-free.
//  - segment_sum: EXACT ascending-pixel-index sequential adds per cluster.
// R27 (257.8us, BEST): latency-chain cuts — update's per-element LDS bsearch
// replaced by parallel per-tile nmap fill; assign centers k-major in regs;
// direct global scatter of sorted indices. 4 barriers in assign.
// R28 (274us, REVERTED): TPX=1024 regressed +16us — proved dispatches are
// per-BLOCK critical-path-bound (4 serial EVALKs/cluster + 4x ballot loops
// outweighed halved block count). R29 = R27 verbatim (measured optimum).
// Structure floor ~258us: 41us harness ws-fill + ~27us x 21 graph-replay
// boundaries (R23: in-kernel sync >= 11us/sync, strictly worse) + ~185us
// latency-chain phase work (instruction-level cuts measured near-neutral
// R25-R27; work-amortization measured negative R28).

#pragma clang fp contract(off)

#define BATCH 8
#define HH 224
#define WW 224
#define HWPIX (HH * WW)        // 50176
#define KSEG 100
#define TPX 512                // pixels per tile
#define NTILE 98               // 512-px tiles per batch (98*512 == 50176)
#define NITER 10
#define UCH 1024               // update output chunk
#define UPITCH (UCH + 4)       // row stride: 4112B = 257*16, 16B-aligned

__device__ __forceinline__ float get_ratio() {
    double S = sqrt((double)(HH * WW) / (double)KSEG);
    return (float)(10.0 / S);
}

// 2 pixels/thread: n = tile*512 + p*256 + tid. Ascending n == lex (p, w, lane).
// mode 2: first iteration — init centers computed locally (== old k_init),
//         tile-0 also writes them to global; then argmin + sort as mode 0.
// mode 0: argmin (pruned) + tile-local counting sort -> tileIdx + cntStart.
// mode 1: final outputs only.
__global__ void k_assign(const float* __restrict__ img, float* __restrict__ centers,
                         int* __restrict__ tileIdx, int2* __restrict__ cntStart,
                         float* __restrict__ outLab, float* __restrict__ outMean,
                         int mode) {
#pragma clang fp contract(off)
    __shared__ float c8[KSEG * 8];   // [c0..c4, csq, pad, pad]
    __shared__ int whist[8 * KSEG];  // group g = p*4 + w; becomes excl. prefix
    __shared__ int tilecnt[KSEG];
    __shared__ int loffs[KSEG];
    int b = blockIdx.y, tile = blockIdx.x, tid = threadIdx.x;
    int lane = tid & 63, w = tid >> 6;
    float ratio = get_ratio();

    // ---- phase 0: centers k-major into registers, csq seq-adds, ONE LDS write
    if (mode == 2) {
        // init centers locally: pure function of img, identical exprs to the
        // old k_init -> bit-identical values.
        if (tid < KSEG) {
            int k = tid;
            int i = k / 10, j = k % 10;
            int y = (int)floor(((i + 0.5) * (double)HH) / 10.0);
            int x = (int)floor(((j + 0.5) * (double)WW) / 10.0);
            int n = y * WW + x;
            const float* p = img + ((size_t)b * HWPIX + n) * 3;
            float c0 = (float)y * ratio, c1 = (float)x * ratio;
            float c2 = p[0], c3 = p[1], c4 = p[2];
            float s = c0 * c0;               // XLA fused mul+reduce: no fma
            s = s + c1 * c1;
            s = s + c2 * c2;
            s = s + c3 * c3;
            s = s + c4 * c4;
            float* cw = c8 + k * 8;
            cw[0] = c0; cw[1] = c1; cw[2] = c2; cw[3] = c3; cw[4] = c4; cw[5] = s;
            if (tile == 0) {     // global init: covers total==0 keep-old case
                float* c = centers + (b * KSEG + k) * 5;
                c[0] = c0; c[1] = c1; c[2] = c2; c[3] = c3; c[4] = c4;
            }
        }
    } else {
        if (tid < KSEG) {
            const float* cg = centers + ((size_t)b * KSEG + tid) * 5;
            float c0 = cg[0], c1 = cg[1], c2 = cg[2], c3 = cg[3], c4 = cg[4];
            float s = c0 * c0;               // same seq-add order as ever
            s = s + c1 * c1;
            s = s + c2 * c2;
            s = s + c3 * c3;
            s = s + c4 * c4;
            float* cw = c8 + tid * 8;
            cw[0] = c0; cw[1] = c1; cw[2] = c2; cw[3] = c3; cw[4] = c4; cw[5] = s;
        }
    }
    if (mode != 1)
        for (int i = tid; i < 8 * KSEG; i += 256) whist[i] = 0;

    // ---- pixel features (registers only; overlaps the loads above)
    int n0 = tile * TPX + tid;
    float yf[2], xf[2], rr[2], gg[2], bb[2], fsq[2], dmin[2];
    int kb[2];
#pragma unroll
    for (int p = 0; p < 2; ++p) {
        int n = n0 + p * 256;
        int y = n / WW, x = n - y * WW;
        yf[p] = (float)y * ratio;
        xf[p] = (float)x * ratio;
        const float* pp = img + ((size_t)b * HWPIX + n) * 3;
        rr[p] = pp[0]; gg[p] = pp[1]; bb[p] = pp[2];
        float s = yf[p] * yf[p];             // no fma, seq adds (XLA reduce)
        s = s + xf[p] * xf[p];
        s = s + rr[p] * rr[p];
        s = s + gg[p] * gg[p];
        s = s + bb[p] * bb[p];
        fsq[p] = s;
        dmin[p] = INFINITY;
        kb[p] = 0;
    }
    __syncthreads();                                 // (A) c8 + whist ready

    // evaluate one cluster exactly (reference op order); order-free first-min rule
#define EVALK(kk)                                                              \
    {                                                                          \
        int k_ = (kk);                                                         \
        float4 v0 = *reinterpret_cast<const float4*>(&c8[k_ * 8]);             \
        float2 v1 = *reinterpret_cast<const float2*>(&c8[k_ * 8 + 4]);         \
        _Pragma("unroll")                                                      \
        for (int p = 0; p < 2; ++p) {                                          \
            float dot = yf[p] * v0.x;                                          \
            dot = __fmaf_rn(xf[p], v0.y, dot);                                 \
            dot = __fmaf_rn(rr[p], v0.z, dot);                                 \
            dot = __fmaf_rn(gg[p], v0.w, dot);                                 \
            dot = __fmaf_rn(bb[p], v1.x, dot);                                 \
            float d = (fsq[p] + v1.y) - 2.0f * dot;                            \
            if (d < dmin[p] || (d == dmin[p] && k_ < kb[p])) {                 \
                dmin[p] = d; kb[p] = k_;                                       \
            }                                                                  \
        }                                                                      \
    }

    // ---- phase A: statically nearest cluster grid rows (ascending k)
    int y0t = (tile * TPX) / WW, y1t = (tile * TPX + TPX - 1) / WW;
    int rmid = ((y0t + y1t) / 2) * 10 / HH;          // nearest init grid row
    int rlo = (rmid > 0) ? rmid - 1 : 0;
    int rhi = (rmid < 9) ? rmid + 1 : 9;
    int kA0 = rlo * 10, kA1 = rhi * 10 + 10;         // 20..30 clusters
    for (int k = kA0; k < kA1; ++k) EVALK(k);

    // ---- per-WAVE max dmin + rigorous margin (no LDS, no barriers)
    float tmax = fmaxf(dmin[0], dmin[1]);
    for (int d = 32; d > 0; d >>= 1) tmax = fmaxf(tmax, __shfl_xor(tmax, d));
    float dmaxW = tmax + 1.0f;

    // ---- per-wave keep-mask: remaining ks whose y lower bound could still win
    unsigned long long m0, m1;
    {
        int k1 = lane;                               // k 0..63
        bool instat1 = (k1 >= kA0 && k1 < kA1);
        float cyf1 = c8[k1 * 8 + 0];
        float t01 = (float)y0t * ratio - cyf1;       // cy below tile range
        float t11 = cyf1 - (float)y1t * ratio;       // cy above tile range
        float t1v = fmaxf(fmaxf(t01, t11), 0.0f);
        m0 = __ballot((!instat1) && (t1v * t1v <= dmaxW));
        int k2 = 64 + lane;                          // k 64..99 (lane<36)
        bool keep2 = false;
        if (k2 < KSEG) {
            bool instat2 = (k2 >= kA0 && k2 < kA1);
            float cyf2 = c8[k2 * 8 + 0];
            float t02 = (float)y0t * ratio - cyf2;
            float t12 = cyf2 - (float)y1t * ratio;
            float t2v = fmaxf(fmaxf(t02, t12), 0.0f);
            keep2 = (!instat2) && (t2v * t2v <= dmaxW);
        }
        m1 = __ballot(keep2);
    }

    // ---- phase B: surviving clusters (ascending k within each word)
    while (m0) { int k = __builtin_ctzll(m0); m0 &= m0 - 1; EVALK(k); }
    while (m1) { int k = 64 + __builtin_ctzll(m1); m1 &= m1 - 1; EVALK(k); }
#undef EVALK

    if (mode == 1) {
#pragma unroll
        for (int p = 0; p < 2; ++p) {
            int n = n0 + p * 256;
            outLab[(size_t)b * HWPIX + n] = (float)kb[p];
            float* om = outMean + ((size_t)b * HWPIX + n) * 3;
            om[0] = c8[kb[p] * 8 + 2];
            om[1] = c8[kb[p] * 8 + 3];
            om[2] = c8[kb[p] * 8 + 4];
        }
        return;
    }

    // ---- tile-local stable counting sort (order: p, wave, lane == ascending n)
    // Leader-ballot rank over DISTINCT labels present in the wave.
    unsigned long long lmask_lt = (lane == 0) ? 0ull : (~0ull >> (64 - lane));
    int rank_w[2], cnt_w[2];
#pragma unroll
    for (int p = 0; p < 2; ++p) {
        unsigned long long todo = __ballot(1);       // all active lanes
        while (todo) {
            int leader = __builtin_ctzll(todo);
            int lval = __shfl(kb[p], leader);
            unsigned long long mset = __ballot(kb[p] == lval);
            if (kb[p] == lval) {
                cnt_w[p] = (int)__popcll(mset);
                rank_w[p] = (int)__popcll(mset & lmask_lt);
            }
            todo &= ~mset;
        }
    }
#pragma unroll
    for (int p = 0; p < 2; ++p)
        if (rank_w[p] == 0) whist[(p * 4 + w) * KSEG + kb[p]] = cnt_w[p];
    __syncthreads();                                 // (B)
    if (tid < KSEG) {
        int s = 0;
#pragma unroll
        for (int g = 0; g < 8; ++g) {                // sum AND leave exclusive
            int t = whist[g * KSEG + tid];           // prefix in place
            whist[g * KSEG + tid] = s;
            s += t;
        }
        tilecnt[tid] = s;
    }
    __syncthreads();                                 // (C)
    // exclusive scan of tilecnt[100]: ONE wave, two chunks, in-wave carry
    if (tid < 64) {
        int v = tilecnt[lane];
        int incl = v;
        for (int d = 1; d < 64; d <<= 1) {
            int t = __shfl_up(incl, d);
            if (lane >= d) incl += t;
        }
        loffs[lane] = incl - v;
        int carry = __shfl(incl, 63);
        int i2 = 64 + lane;                          // k 64..99
        int v2 = (i2 < KSEG) ? tilecnt[i2] : 0;
        int incl2 = v2;
        for (int d = 1; d < 64; d <<= 1) {
            int t = __shfl_up(incl2, d);
            if (lane >= d) incl2 += t;
        }
        if (i2 < KSEG) loffs[i2] = carry + incl2 - v2;
    }
    __syncthreads();                                 // (D)
    if (tid < KSEG) {
        cntStart[((size_t)b * KSEG + tid) * NTILE + tile] =
            make_int2(tilecnt[tid], loffs[tid]);     // one dwordx2
    }

    // ---- DIRECT global scatter of sorted pixel indices (same integers as the
    // old LDS-stage+copy; same-label lanes hit consecutive addresses)
    int* tb = tileIdx + (size_t)(b * NTILE + tile) * TPX;
#pragma unroll
    for (int p = 0; p < 2; ++p) {
        int g = p * 4 + w;
        int pos = loffs[kb[p]] + rank_w[p] + whist[g * KSEG + kb[p]];
        tb[pos] = n0 + p * 256;                      // pixel index, asc per seg
    }
}

// One block per (batch,cluster). Chunked shfl-scan of the 98 descriptors ->
// dstL (+total sentinel). Per chunk: parallel per-TILE fill of nmap (thread t
// streams its tile's intersection of the chunk from tileIdx — independent,
// pipelined loads), then all 256 threads gather: RE-DERIVE the 5 channels
// (y=n/224 exact int div; yf=(float)y*ratio identical expression to assign;
// r,g,b from img) into ubuf. Then 5 lanes run the EXACT ascending serial
// chains via pipelined float4 LDS reads (x,y,z,w index order).
__global__ void k_update(const float* __restrict__ img, const int* __restrict__ tileIdx,
                         const int2* __restrict__ cntStart, float* __restrict__ centers) {
#pragma clang fp contract(off)
    __shared__ int srcL[NTILE];
    __shared__ int dstL[NTILE + 1];
    __shared__ int nmap[UCH];
    __shared__ float ubuf[5][UPITCH];
    int k = blockIdx.x, b = blockIdx.y, tid = threadIdx.x;
    int lane = tid & 63;
    float ratio = get_ratio();

    if (tid < 64) {
        int carry = 0;
        for (int c0 = 0; c0 < NTILE; c0 += 64) {
            int idx = c0 + lane;
            int2 cs = (idx < NTILE)
                ? cntStart[((size_t)b * KSEG + k) * NTILE + idx] : make_int2(0, 0);
            int incl = cs.x;
            for (int d = 1; d < 64; d <<= 1) {   // Hillis-Steele inclusive scan
                int t = __shfl_up(incl, d);
                if (lane >= d) incl += t;
            }
            if (idx < NTILE) { srcL[idx] = cs.y; dstL[idx] = carry + incl - cs.x; }
            carry += __shfl(incl, 63);
        }
        if (lane == 0) dstL[NTILE] = carry;
    }
    __syncthreads();
    int total = dstL[NTILE];

    float acc = 0.f;
    for (int c0 = 0; c0 < total; c0 += UCH) {
        int m = min(UCH, total - c0);
        // ---- parallel fill: thread t streams its tile's slice of this chunk
        if (tid < NTILE) {
            int t = tid;
            int d0 = dstL[t], d1 = dstL[t + 1];
            int lo = d0 > c0 ? d0 : c0;
            int hi = d1 < c0 + m ? d1 : c0 + m;
            if (lo < hi) {
                const int* tip = tileIdx + (size_t)(b * NTILE + t) * TPX
                                 + (srcL[t] + (lo - d0));
                for (int i = lo; i < hi; ++i)
                    nmap[i - c0] = tip[i - lo];      // independent loads, pipeline
            }
        }
        __syncthreads();
        // ---- gather: short chain nmap(LDS) -> img
        for (int jj = tid; jj < m; jj += 256) {
            int n = nmap[jj];
            int y = n / WW, x = n - y * WW;  // exact integer magic-div
            const float* pp = img + ((size_t)b * HWPIX + n) * 3;
            ubuf[0][jj] = (float)y * ratio;  // bit-identical to assign's yf
            ubuf[1][jj] = (float)x * ratio;
            ubuf[2][jj] = pp[0];
            ubuf[3][jj] = pp[1];
            ubuf[4][jj] = pp[2];
        }
        __syncthreads();
        if (tid < 5) {
            float a = acc;
            const float4* bp4 = reinterpret_cast<const float4*>(&ubuf[tid][0]);
            int nf4 = m >> 2;
#pragma unroll 4
            for (int i = 0; i < nf4; ++i) {  // loads pipeline; adds ascending
                float4 v = bp4[i];
                a = a + v.x;
                a = a + v.y;
                a = a + v.z;
                a = a + v.w;
            }
            for (int i = nf4 << 2; i < m; ++i) a = a + ubuf[tid][i];
            acc = a;
        }
        __syncthreads();
    }
    if (tid < 5 && total > 0) {              // where(counts>0, sums/counts, old)
        centers[(b * KSEG + k) * 5 + tid] = acc / (float)total;
    }
}

extern "C" void kernel_launch(void* const* d_in, const int* in_sizes, int n_in,
                              void* d_out, int out_size, void* d_ws, size_t ws_size,
                              hipStream_t stream) {
    const float* img = (const float*)d_in[0];
    float* outLab = (float*)d_out;                         // [8,224,224] labels as f32
    float* outMean = outLab + (size_t)BATCH * HWPIX;       // [8,224,224,3]

    char* ws = (char*)d_ws;
    float* centers = (float*)ws;  ws += (size_t)BATCH * KSEG * 5 * sizeof(float);
    int* tileIdx   = (int*)ws;    ws += (size_t)BATCH * NTILE * TPX * sizeof(int);
    int2* cntStart = (int2*)ws;   ws += (size_t)BATCH * KSEG * NTILE * sizeof(int2);

    for (int it = 0; it < NITER; ++it) {
        k_assign<<<dim3(NTILE, BATCH), 256, 0, stream>>>(
            img, centers, tileIdx, cntStart, outLab, outMean, it == 0 ? 2 : 0);
        k_update<<<dim3(KSEG, BATCH), 256, 0, stream>>>(img, tileIdx, cntStart,
                                                        centers);
    }
    k_assign<<<dim3(NTILE, BATCH), 256, 0, stream>>>(
        img, centers, tileIdx, cntStart, outLab, outMean, 1);
}